// Round 11
// baseline (508.323 us; speedup 1.0000x reference)
//
#include <hip/hip_runtime.h>

// LinearKernelAttention: out = normalize_row(mask0(QK^T + 1e-5)) @ V
// R10 result: 195us, ALL pipes <40% (VALU 37, MFMA 14, HBM 11), occupancy
// 23% (2 blocks/CU) -> latency/barrier-bound, not pipe-bound.
// R11: occupancy 2->4 blocks/CU. Q-staging LDS (18.4KB) was dead after the
// register hoist -> alias Q staging into Kh/Kl; LDS 56.3->37.9KB;
// __launch_bounds__(256,4). No other changes (attribution).
//
// Shapes: B=2, H=16, S=2048, D=64, fp32 in/out, mask int32 [B,1,S,S].

constexpr int Sdim = 2048;
constexpr int Ddim = 64;
constexpr int BQ = 64;
constexpr int BK = 64;
constexpr int LD = 72;   // bf16 elems/row: 144B rows -> 16B-aligned, bank-balanced

typedef __attribute__((ext_vector_type(8))) short short8;
typedef __attribute__((ext_vector_type(4))) float f32x4;

#define MFMA(acc, a, b) (acc) = __builtin_amdgcn_mfma_f32_16x16x32_bf16((a), (b), (acc), 0, 0, 0)

__device__ __forceinline__ unsigned bf_hi(float x) {   // bf16 RNE, low 16 bits
    union { float f; unsigned u; } v; v.f = x;
    return (v.u + 0x7fffu + ((v.u >> 16) & 1u)) >> 16;
}
__device__ __forceinline__ float bf_f(unsigned h) {
    union { unsigned u; float f; } v; v.u = h << 16; return v.f;
}

__global__ __launch_bounds__(256, 4) void lka_mfma(
    const float* __restrict__ Q, const float* __restrict__ K,
    const float* __restrict__ V, const int* __restrict__ M,
    float* __restrict__ O)
{
    // Kh/Kl double as the Q staging buffers before the k-loop.
    __shared__ unsigned short Kh[BK * LD], Kl[BK * LD];
    __shared__ unsigned short Vh[Ddim * LD];   // transposed [d][key], key-blocks swizzled by d>>3
    __shared__ unsigned short Ph[BQ * LD];
    __shared__ float ssq_tab[4][BQ];

    const int tid  = threadIdx.x;
    const int w    = tid >> 6;        // wave 0..3
    const int lane = tid & 63;
    const int l15  = lane & 15;
    const int g    = lane >> 4;       // 0..3
    const int bh   = blockIdx.y;
    const int b    = bh >> 4;         // H = 16
    const int q0   = blockIdx.x * BQ;

    const float* Qp = Q + (size_t)bh * Sdim * Ddim;
    const float* Kp = K + (size_t)bh * Sdim * Ddim;
    const float* Vp = V + (size_t)bh * Sdim * Ddim;
    const int*   Mp = M + (size_t)b * Sdim * Sdim;
    float*       Op = O + (size_t)bh * Sdim * Ddim;

    // ---- stage Q tile into Kh/Kl (hi/lo split), coalesced float4 ----
#pragma unroll
    for (int it = 0; it < 4; ++it) {
        int idx = tid + it * 256;
        int row = idx >> 4, c4 = idx & 15;
        float4 v = *(const float4*)(Qp + (size_t)(q0 + row) * Ddim + c4 * 4);
        unsigned h0 = bf_hi(v.x), h1 = bf_hi(v.y), h2 = bf_hi(v.z), h3 = bf_hi(v.w);
        *(uint2*)(&Kh[row * LD + c4 * 4]) = make_uint2(h0 | (h1 << 16), h2 | (h3 << 16));
        *(uint2*)(&Kl[row * LD + c4 * 4]) = make_uint2(
            bf_hi(v.x - bf_f(h0)) | (bf_hi(v.y - bf_f(h1)) << 16),
            bf_hi(v.z - bf_f(h2)) | (bf_hi(v.w - bf_f(h3)) << 16));
    }
    __syncthreads();

    // ---- hoist Q fragments to registers (k-invariant B-operands) ----
#define QFRAG(t)                                                               \
    short8 qb##t##h0, qb##t##h1, qb##t##l0, qb##t##l1;                         \
    {                                                                          \
        const int brow = 16 * (t) + l15;                                       \
        qb##t##h0 = *(const short8*)(&Kh[brow * LD + g * 8]);                  \
        qb##t##h1 = *(const short8*)(&Kh[brow * LD + 32 + g * 8]);             \
        qb##t##l0 = *(const short8*)(&Kl[brow * LD + g * 8]);                  \
        qb##t##l1 = *(const short8*)(&Kl[brow * LD + 32 + g * 8]);             \
    }
    QFRAG(0) QFRAG(1) QFRAG(2) QFRAG(3)
#undef QFRAG

    f32x4 acc0 = {0.f,0.f,0.f,0.f}, acc1 = {0.f,0.f,0.f,0.f};
    f32x4 acc2 = {0.f,0.f,0.f,0.f}, acc3 = {0.f,0.f,0.f,0.f};
    float ssq0 = 0.f, ssq1 = 0.f, ssq2 = 0.f, ssq3 = 0.f;

    for (int k0 = 0; k0 < Sdim; k0 += BK) {
        __syncthreads();   // prev tile (and Q-frag hoist) done reading Kh/Kl/Vh/Ph

        // ---- stage K (row-major hi/lo) and V (transposed hi, swizzled) ----
#pragma unroll
        for (int it = 0; it < 4; ++it) {
            int idx = tid + it * 256;
            int row = idx >> 4, c4 = idx & 15;
            {
                float4 v = *(const float4*)(Kp + (size_t)(k0 + row) * Ddim + c4 * 4);
                unsigned h0 = bf_hi(v.x), h1 = bf_hi(v.y), h2 = bf_hi(v.z), h3 = bf_hi(v.w);
                *(uint2*)(&Kh[row * LD + c4 * 4]) = make_uint2(h0 | (h1 << 16), h2 | (h3 << 16));
                *(uint2*)(&Kl[row * LD + c4 * 4]) = make_uint2(
                    bf_hi(v.x - bf_f(h0)) | (bf_hi(v.y - bf_f(h1)) << 16),
                    bf_hi(v.z - bf_f(h2)) | (bf_hi(v.w - bf_f(h3)) << 16));
            }
            {
                float4 v = *(const float4*)(Vp + (size_t)(k0 + row) * Ddim + c4 * 4);
                int kb = row >> 3, ko = row & 7;   // key block / key offset
#define VSTORE(i, comp)                                                        \
                {                                                              \
                    int d = c4 * 4 + (i);                                      \
                    int off = d * LD + (((kb ^ (d >> 3)) << 3) | ko);          \
                    Vh[off] = (unsigned short)bf_hi(v.comp);                   \
                }
                VSTORE(0, x) VSTORE(1, y) VSTORE(2, z) VSTORE(3, w)
#undef VSTORE
            }
        }
        __syncthreads();

        // ---- QK^T swapped: A = K rows (wave's 16 keys), B = hoisted Q ----
        // C layout: col=q_local=l15, row=key_local=4g+reg
        const int arow = 16 * w + l15;
        short8 aKh0 = *(const short8*)(&Kh[arow * LD + g * 8]);
        short8 aKh1 = *(const short8*)(&Kh[arow * LD + 32 + g * 8]);
        short8 aKl0 = *(const short8*)(&Kl[arow * LD + g * 8]);
        short8 aKl1 = *(const short8*)(&Kl[arow * LD + 32 + g * 8]);

#define QKT_TILE(t, sacc)                                                      \
        f32x4 sacc = {0.f, 0.f, 0.f, 0.f};                                     \
        {                                                                      \
            MFMA(sacc, aKh0, qb##t##h0); MFMA(sacc, aKh1, qb##t##h1);          \
            MFMA(sacc, aKh0, qb##t##l0); MFMA(sacc, aKh1, qb##t##l1);          \
            MFMA(sacc, aKl0, qb##t##h0); MFMA(sacc, aKl1, qb##t##h1);          \
        }
        QKT_TILE(0, s0) QKT_TILE(1, s1) QKT_TILE(2, s2) QKT_TILE(3, s3)
#undef QKT_TILE

        // ---- mask + eps, ssq accumulate (fp32, pre-quantization), park P ----
        const int kcol = k0 + 16 * w + 4 * g;     // 4 contiguous keys: +reg
#define PARK(t, sacc, ssq)                                                     \
        {                                                                      \
            const int qrow = q0 + 16 * (t) + l15;                              \
            int4 mm = *(const int4*)(Mp + (size_t)qrow * Sdim + kcol);         \
            float x0 = mm.x ? sacc.x + 1e-5f : 0.f;                            \
            float x1 = mm.y ? sacc.y + 1e-5f : 0.f;                            \
            float x2 = mm.z ? sacc.z + 1e-5f : 0.f;                            \
            float x3 = mm.w ? sacc.w + 1e-5f : 0.f;                            \
            ssq += x0 * x0 + x1 * x1 + x2 * x2 + x3 * x3;                      \
            int po = (16 * (t) + l15) * LD + 16 * w + 4 * g;                   \
            *(uint2*)(&Ph[po]) = make_uint2(bf_hi(x0) | (bf_hi(x1) << 16),     \
                                            bf_hi(x2) | (bf_hi(x3) << 16));   \
        }
        PARK(0, s0, ssq0) PARK(1, s1, ssq1) PARK(2, s2, ssq2) PARK(3, s3, ssq3)
#undef PARK
        __syncthreads();

        // ---- PV: A = P rows (wave's 16 q), B = V^T (swizzled blocks) ----
        const int prow = 16 * w + l15;
        short8 aPh0 = *(const short8*)(&Ph[prow * LD + g * 8]);
        short8 aPh1 = *(const short8*)(&Ph[prow * LD + 32 + g * 8]);

#define PV_TILE(t, acc)                                                        \
        {                                                                      \
            const int drow = 16 * (t) + l15;                                   \
            const int sw = drow >> 3;                                          \
            short8 vb0 = *(const short8*)(&Vh[drow * LD + (((0 + g) ^ sw) << 3)]); \
            short8 vb1 = *(const short8*)(&Vh[drow * LD + (((4 + g) ^ sw) << 3)]); \
            MFMA(acc, aPh0, vb0); MFMA(acc, aPh1, vb1);                        \
        }
        PV_TILE(0, acc0) PV_TILE(1, acc1) PV_TILE(2, acc2) PV_TILE(3, acc3)
#undef PV_TILE
    }

    // ---- ssq: reduce over key-groups in-wave, then across waves via LDS ----
    ssq0 += __shfl_xor(ssq0, 16, 64); ssq0 += __shfl_xor(ssq0, 32, 64);
    ssq1 += __shfl_xor(ssq1, 16, 64); ssq1 += __shfl_xor(ssq1, 32, 64);
    ssq2 += __shfl_xor(ssq2, 16, 64); ssq2 += __shfl_xor(ssq2, 32, 64);
    ssq3 += __shfl_xor(ssq3, 16, 64); ssq3 += __shfl_xor(ssq3, 32, 64);
    if (lane < 16) {
        ssq_tab[w][l15]      = ssq0;
        ssq_tab[w][16 + l15] = ssq1;
        ssq_tab[w][32 + l15] = ssq2;
        ssq_tab[w][48 + l15] = ssq3;
    }
    __syncthreads();

    // ---- scale rows by 1/max(||s||,1e-12) and store ----
#define OUTR(reg, comp)                                                        \
    {                                                                          \
        const int q = 16 * w + 4 * g + (reg);                                  \
        float sum = ssq_tab[0][q] + ssq_tab[1][q] + ssq_tab[2][q] + ssq_tab[3][q]; \
        float rn = 1.0f / fmaxf(sqrtf(sum), 1e-12f);                           \
        float* orow = Op + (size_t)(q0 + q) * Ddim + l15;                      \
        orow[0]  = acc0.comp * rn;                                             \
        orow[16] = acc1.comp * rn;                                             \
        orow[32] = acc2.comp * rn;                                             \
        orow[48] = acc3.comp * rn;                                             \
    }
    OUTR(0, x) OUTR(1, y) OUTR(2, z) OUTR(3, w)
#undef OUTR
}

extern "C" void kernel_launch(void* const* d_in, const int* in_sizes, int n_in,
                              void* d_out, int out_size, void* d_ws, size_t ws_size,
                              hipStream_t stream) {
    const float* Q = (const float*)d_in[0];
    const float* K = (const float*)d_in[1];
    const float* V = (const float*)d_in[2];
    const int*   M = (const int*)d_in[3];
    float*       O = (float*)d_out;

    const int BH = in_sizes[0] / (Sdim * Ddim);  // B*H = 32
    dim3 grid(Sdim / BQ, BH);
    lka_mfma<<<grid, dim3(256), 0, stream>>>(Q, K, V, M, O);
}

// Round 12
// 429.747 us; speedup vs baseline: 1.1828x; 1.1828x over previous
//
#include <hip/hip_runtime.h>

// LinearKernelAttention: out = normalize_row(mask0(QK^T + 1e-5)) @ V
// R11 result: launch_bounds(256,4) VGPR-capped to 64 -> massive scratch
// spill (WRITE 16->62MB, FETCH 156->845MB), dur 195->427us. Occupancy won,
// spill lost. Kernel needs ~108 VGPR live.
// R12: launch_bounds(256,3) -> cap 170 VGPR (no spill), 3 blocks/CU
// (12 waves/CU, 1.5x R10 TLP). Single edit vs R11.
//
// Shapes: B=2, H=16, S=2048, D=64, fp32 in/out, mask int32 [B,1,S,S].

constexpr int Sdim = 2048;
constexpr int Ddim = 64;
constexpr int BQ = 64;
constexpr int BK = 64;
constexpr int LD = 72;   // bf16 elems/row: 144B rows -> 16B-aligned, bank-balanced

typedef __attribute__((ext_vector_type(8))) short short8;
typedef __attribute__((ext_vector_type(4))) float f32x4;

#define MFMA(acc, a, b) (acc) = __builtin_amdgcn_mfma_f32_16x16x32_bf16((a), (b), (acc), 0, 0, 0)

__device__ __forceinline__ unsigned bf_hi(float x) {   // bf16 RNE, low 16 bits
    union { float f; unsigned u; } v; v.f = x;
    return (v.u + 0x7fffu + ((v.u >> 16) & 1u)) >> 16;
}
__device__ __forceinline__ float bf_f(unsigned h) {
    union { unsigned u; float f; } v; v.u = h << 16; return v.f;
}

__global__ __launch_bounds__(256, 3) void lka_mfma(
    const float* __restrict__ Q, const float* __restrict__ K,
    const float* __restrict__ V, const int* __restrict__ M,
    float* __restrict__ O)
{
    // Kh/Kl double as the Q staging buffers before the k-loop.
    __shared__ unsigned short Kh[BK * LD], Kl[BK * LD];
    __shared__ unsigned short Vh[Ddim * LD];   // transposed [d][key], key-blocks swizzled by d>>3
    __shared__ unsigned short Ph[BQ * LD];
    __shared__ float ssq_tab[4][BQ];

    const int tid  = threadIdx.x;
    const int w    = tid >> 6;        // wave 0..3
    const int lane = tid & 63;
    const int l15  = lane & 15;
    const int g    = lane >> 4;       // 0..3
    const int bh   = blockIdx.y;
    const int b    = bh >> 4;         // H = 16
    const int q0   = blockIdx.x * BQ;

    const float* Qp = Q + (size_t)bh * Sdim * Ddim;
    const float* Kp = K + (size_t)bh * Sdim * Ddim;
    const float* Vp = V + (size_t)bh * Sdim * Ddim;
    const int*   Mp = M + (size_t)b * Sdim * Sdim;
    float*       Op = O + (size_t)bh * Sdim * Ddim;

    // ---- stage Q tile into Kh/Kl (hi/lo split), coalesced float4 ----
#pragma unroll
    for (int it = 0; it < 4; ++it) {
        int idx = tid + it * 256;
        int row = idx >> 4, c4 = idx & 15;
        float4 v = *(const float4*)(Qp + (size_t)(q0 + row) * Ddim + c4 * 4);
        unsigned h0 = bf_hi(v.x), h1 = bf_hi(v.y), h2 = bf_hi(v.z), h3 = bf_hi(v.w);
        *(uint2*)(&Kh[row * LD + c4 * 4]) = make_uint2(h0 | (h1 << 16), h2 | (h3 << 16));
        *(uint2*)(&Kl[row * LD + c4 * 4]) = make_uint2(
            bf_hi(v.x - bf_f(h0)) | (bf_hi(v.y - bf_f(h1)) << 16),
            bf_hi(v.z - bf_f(h2)) | (bf_hi(v.w - bf_f(h3)) << 16));
    }
    __syncthreads();

    // ---- hoist Q fragments to registers (k-invariant B-operands) ----
#define QFRAG(t)                                                               \
    short8 qb##t##h0, qb##t##h1, qb##t##l0, qb##t##l1;                         \
    {                                                                          \
        const int brow = 16 * (t) + l15;                                       \
        qb##t##h0 = *(const short8*)(&Kh[brow * LD + g * 8]);                  \
        qb##t##h1 = *(const short8*)(&Kh[brow * LD + 32 + g * 8]);             \
        qb##t##l0 = *(const short8*)(&Kl[brow * LD + g * 8]);                  \
        qb##t##l1 = *(const short8*)(&Kl[brow * LD + 32 + g * 8]);             \
    }
    QFRAG(0) QFRAG(1) QFRAG(2) QFRAG(3)
#undef QFRAG

    f32x4 acc0 = {0.f,0.f,0.f,0.f}, acc1 = {0.f,0.f,0.f,0.f};
    f32x4 acc2 = {0.f,0.f,0.f,0.f}, acc3 = {0.f,0.f,0.f,0.f};
    float ssq0 = 0.f, ssq1 = 0.f, ssq2 = 0.f, ssq3 = 0.f;

    for (int k0 = 0; k0 < Sdim; k0 += BK) {
        __syncthreads();   // prev tile (and Q-frag hoist) done reading Kh/Kl/Vh/Ph

        // ---- stage K (row-major hi/lo) and V (transposed hi, swizzled) ----
#pragma unroll
        for (int it = 0; it < 4; ++it) {
            int idx = tid + it * 256;
            int row = idx >> 4, c4 = idx & 15;
            {
                float4 v = *(const float4*)(Kp + (size_t)(k0 + row) * Ddim + c4 * 4);
                unsigned h0 = bf_hi(v.x), h1 = bf_hi(v.y), h2 = bf_hi(v.z), h3 = bf_hi(v.w);
                *(uint2*)(&Kh[row * LD + c4 * 4]) = make_uint2(h0 | (h1 << 16), h2 | (h3 << 16));
                *(uint2*)(&Kl[row * LD + c4 * 4]) = make_uint2(
                    bf_hi(v.x - bf_f(h0)) | (bf_hi(v.y - bf_f(h1)) << 16),
                    bf_hi(v.z - bf_f(h2)) | (bf_hi(v.w - bf_f(h3)) << 16));
            }
            {
                float4 v = *(const float4*)(Vp + (size_t)(k0 + row) * Ddim + c4 * 4);
                int kb = row >> 3, ko = row & 7;   // key block / key offset
#define VSTORE(i, comp)                                                        \
                {                                                              \
                    int d = c4 * 4 + (i);                                      \
                    int off = d * LD + (((kb ^ (d >> 3)) << 3) | ko);          \
                    Vh[off] = (unsigned short)bf_hi(v.comp);                   \
                }
                VSTORE(0, x) VSTORE(1, y) VSTORE(2, z) VSTORE(3, w)
#undef VSTORE
            }
        }
        __syncthreads();

        // ---- QK^T swapped: A = K rows (wave's 16 keys), B = hoisted Q ----
        // C layout: col=q_local=l15, row=key_local=4g+reg
        const int arow = 16 * w + l15;
        short8 aKh0 = *(const short8*)(&Kh[arow * LD + g * 8]);
        short8 aKh1 = *(const short8*)(&Kh[arow * LD + 32 + g * 8]);
        short8 aKl0 = *(const short8*)(&Kl[arow * LD + g * 8]);
        short8 aKl1 = *(const short8*)(&Kl[arow * LD + 32 + g * 8]);

#define QKT_TILE(t, sacc)                                                      \
        f32x4 sacc = {0.f, 0.f, 0.f, 0.f};                                     \
        {                                                                      \
            MFMA(sacc, aKh0, qb##t##h0); MFMA(sacc, aKh1, qb##t##h1);          \
            MFMA(sacc, aKh0, qb##t##l0); MFMA(sacc, aKh1, qb##t##l1);          \
            MFMA(sacc, aKl0, qb##t##h0); MFMA(sacc, aKl1, qb##t##h1);          \
        }
        QKT_TILE(0, s0) QKT_TILE(1, s1) QKT_TILE(2, s2) QKT_TILE(3, s3)
#undef QKT_TILE

        // ---- mask + eps, ssq accumulate (fp32, pre-quantization), park P ----
        const int kcol = k0 + 16 * w + 4 * g;     // 4 contiguous keys: +reg
#define PARK(t, sacc, ssq)                                                     \
        {                                                                      \
            const int qrow = q0 + 16 * (t) + l15;                              \
            int4 mm = *(const int4*)(Mp + (size_t)qrow * Sdim + kcol);         \
            float x0 = mm.x ? sacc.x + 1e-5f : 0.f;                            \
            float x1 = mm.y ? sacc.y + 1e-5f : 0.f;                            \
            float x2 = mm.z ? sacc.z + 1e-5f : 0.f;                            \
            float x3 = mm.w ? sacc.w + 1e-5f : 0.f;                            \
            ssq += x0 * x0 + x1 * x1 + x2 * x2 + x3 * x3;                      \
            int po = (16 * (t) + l15) * LD + 16 * w + 4 * g;                   \
            *(uint2*)(&Ph[po]) = make_uint2(bf_hi(x0) | (bf_hi(x1) << 16),     \
                                            bf_hi(x2) | (bf_hi(x3) << 16));   \
        }
        PARK(0, s0, ssq0) PARK(1, s1, ssq1) PARK(2, s2, ssq2) PARK(3, s3, ssq3)
#undef PARK
        __syncthreads();

        // ---- PV: A = P rows (wave's 16 q), B = V^T (swizzled blocks) ----
        const int prow = 16 * w + l15;
        short8 aPh0 = *(const short8*)(&Ph[prow * LD + g * 8]);
        short8 aPh1 = *(const short8*)(&Ph[prow * LD + 32 + g * 8]);

#define PV_TILE(t, acc)                                                        \
        {                                                                      \
            const int drow = 16 * (t) + l15;                                   \
            const int sw = drow >> 3;                                          \
            short8 vb0 = *(const short8*)(&Vh[drow * LD + (((0 + g) ^ sw) << 3)]); \
            short8 vb1 = *(const short8*)(&Vh[drow * LD + (((4 + g) ^ sw) << 3)]); \
            MFMA(acc, aPh0, vb0); MFMA(acc, aPh1, vb1);                        \
        }
        PV_TILE(0, acc0) PV_TILE(1, acc1) PV_TILE(2, acc2) PV_TILE(3, acc3)
#undef PV_TILE
    }

    // ---- ssq: reduce over key-groups in-wave, then across waves via LDS ----
    ssq0 += __shfl_xor(ssq0, 16, 64); ssq0 += __shfl_xor(ssq0, 32, 64);
    ssq1 += __shfl_xor(ssq1, 16, 64); ssq1 += __shfl_xor(ssq1, 32, 64);
    ssq2 += __shfl_xor(ssq2, 16, 64); ssq2 += __shfl_xor(ssq2, 32, 64);
    ssq3 += __shfl_xor(ssq3, 16, 64); ssq3 += __shfl_xor(ssq3, 32, 64);
    if (lane < 16) {
        ssq_tab[w][l15]      = ssq0;
        ssq_tab[w][16 + l15] = ssq1;
        ssq_tab[w][32 + l15] = ssq2;
        ssq_tab[w][48 + l15] = ssq3;
    }
    __syncthreads();

    // ---- scale rows by 1/max(||s||,1e-12) and store ----
#define OUTR(reg, comp)                                                        \
    {                                                                          \
        const int q = 16 * w + 4 * g + (reg);                                  \
        float sum = ssq_tab[0][q] + ssq_tab[1][q] + ssq_tab[2][q] + ssq_tab[3][q]; \
        float rn = 1.0f / fmaxf(sqrtf(sum), 1e-12f);                           \
        float* orow = Op + (size_t)(q0 + q) * Ddim + l15;                      \
        orow[0]  = acc0.comp * rn;                                             \
        orow[16] = acc1.comp * rn;                                             \
        orow[32] = acc2.comp * rn;                                             \
        orow[48] = acc3.comp * rn;                                             \
    }
    OUTR(0, x) OUTR(1, y) OUTR(2, z) OUTR(3, w)
#undef OUTR
}

extern "C" void kernel_launch(void* const* d_in, const int* in_sizes, int n_in,
                              void* d_out, int out_size, void* d_ws, size_t ws_size,
                              hipStream_t stream) {
    const float* Q = (const float*)d_in[0];
    const float* K = (const float*)d_in[1];
    const float* V = (const float*)d_in[2];
    const int*   M = (const int*)d_in[3];
    float*       O = (float*)d_out;

    const int BH = in_sizes[0] / (Sdim * Ddim);  // B*H = 32
    dim3 grid(Sdim / BQ, BH);
    lka_mfma<<<grid, dim3(256), 0, stream>>>(Q, K, V, M, O);
}

// Round 13
// 268.486 us; speedup vs baseline: 1.8933x; 1.6006x over previous
//
#include <hip/hip_runtime.h>

// LinearKernelAttention: out = normalize_row(mask0(QK^T + 1e-5)) @ V
// R11/R12: occupancy >2 blocks/CU always forces VGPR cap below the ~108+
// live requirement -> spill -> slower. Occupancy lever is DEAD; back to
// __launch_bounds__(256,2) (R10 = 193us best).
// R13: hide latency with ILP instead of TLP (T14 async-stage split):
//  - K/V LDS double-buffered (64KB, still 2 blocks/CU)
//  - next tile's 8 global float4 loads issued into named regs BEFORE QK^T,
//    converted+written to the idle buffer after PARK (latency under MFMA)
//  - current tile's 4 mask int4 loads issued at the top too
//  - barriers 3 -> 2 per tile
//
// Shapes: B=2, H=16, S=2048, D=64, fp32 in/out, mask int32 [B,1,S,S].

constexpr int Sdim = 2048;
constexpr int Ddim = 64;
constexpr int BQ = 64;
constexpr int BK = 64;
constexpr int LD = 72;   // bf16 elems/row: 144B rows -> 16B-aligned, bank-balanced

typedef __attribute__((ext_vector_type(8))) short short8;
typedef __attribute__((ext_vector_type(4))) float f32x4;

#define MFMA(acc, a, b) (acc) = __builtin_amdgcn_mfma_f32_16x16x32_bf16((a), (b), (acc), 0, 0, 0)

__device__ __forceinline__ unsigned bf_hi(float x) {   // bf16 RNE, low 16 bits
    union { float f; unsigned u; } v; v.f = x;
    return (v.u + 0x7fffu + ((v.u >> 16) & 1u)) >> 16;
}
__device__ __forceinline__ float bf_f(unsigned h) {
    union { unsigned u; float f; } v; v.u = h << 16; return v.f;
}

__global__ __launch_bounds__(256, 2) void lka_mfma(
    const float* __restrict__ Q, const float* __restrict__ K,
    const float* __restrict__ V, const int* __restrict__ M,
    float* __restrict__ O)
{
    __shared__ unsigned short Kh[2][BK * LD], Kl[2][BK * LD];
    __shared__ unsigned short Vh[2][Ddim * LD];  // transposed [d][key], key-blocks swizzled by d>>3
    __shared__ unsigned short Ph[BQ * LD];
    __shared__ float ssq_tab[4][BQ];

    const int tid  = threadIdx.x;
    const int w    = tid >> 6;        // wave 0..3
    const int lane = tid & 63;
    const int l15  = lane & 15;
    const int g    = lane >> 4;       // 0..3
    const int r0   = tid >> 4;        // staging row base 0..15
    const int c4   = tid & 15;        // staging col group
    const int bh   = blockIdx.y;
    const int b    = bh >> 4;         // H = 16
    const int q0   = blockIdx.x * BQ;

    const float* Qp = Q + (size_t)bh * Sdim * Ddim;
    const float* Kp = K + (size_t)bh * Sdim * Ddim;
    const float* Vp = V + (size_t)bh * Sdim * Ddim;
    const int*   Mp = M + (size_t)b * Sdim * Sdim;
    float*       Op = O + (size_t)bh * Sdim * Ddim;

    // hi/lo split write of one float4 into row-major LDS (K-style)
#define KSTAGE_W(dstH, dstL, row, vreg)                                        \
    {                                                                          \
        unsigned h0 = bf_hi(vreg.x), h1 = bf_hi(vreg.y),                       \
                 h2 = bf_hi(vreg.z), h3 = bf_hi(vreg.w);                       \
        *(uint2*)(&dstH[(row) * LD + c4 * 4]) =                                \
            make_uint2(h0 | (h1 << 16), h2 | (h3 << 16));                      \
        *(uint2*)(&dstL[(row) * LD + c4 * 4]) = make_uint2(                    \
            bf_hi(vreg.x - bf_f(h0)) | (bf_hi(vreg.y - bf_f(h1)) << 16),       \
            bf_hi(vreg.z - bf_f(h2)) | (bf_hi(vreg.w - bf_f(h3)) << 16));      \
    }
    // transposed+swizzled single-bf16 write of one float4 (V-style)
#define VSTAGE_W(dstV, row, vreg)                                              \
    {                                                                          \
        int kb = (row) >> 3, ko = (row) & 7;                                   \
        { int d = c4 * 4 + 0; dstV[d * LD + (((kb ^ (d >> 3)) << 3) | ko)] = (unsigned short)bf_hi(vreg.x); } \
        { int d = c4 * 4 + 1; dstV[d * LD + (((kb ^ (d >> 3)) << 3) | ko)] = (unsigned short)bf_hi(vreg.y); } \
        { int d = c4 * 4 + 2; dstV[d * LD + (((kb ^ (d >> 3)) << 3) | ko)] = (unsigned short)bf_hi(vreg.z); } \
        { int d = c4 * 4 + 3; dstV[d * LD + (((kb ^ (d >> 3)) << 3) | ko)] = (unsigned short)bf_hi(vreg.w); } \
    }

    // ---- prologue: stage Q -> buf1 (as K-style hi/lo), K/V tile0 -> buf0 ----
#pragma unroll
    for (int it = 0; it < 4; ++it) {
        const int row = r0 + 16 * it;
        float4 qv = *(const float4*)(Qp + (size_t)(q0 + row) * Ddim + c4 * 4);
        KSTAGE_W(Kh[1], Kl[1], row, qv);
        float4 kv = *(const float4*)(Kp + (size_t)row * Ddim + c4 * 4);
        KSTAGE_W(Kh[0], Kl[0], row, kv);
        float4 vv = *(const float4*)(Vp + (size_t)row * Ddim + c4 * 4);
        VSTAGE_W(Vh[0], row, vv);
    }
    __syncthreads();

    // ---- hoist Q fragments to registers (k-invariant B-operands) ----
#define QFRAG(t)                                                               \
    short8 qb##t##h0, qb##t##h1, qb##t##l0, qb##t##l1;                         \
    {                                                                          \
        const int brow = 16 * (t) + l15;                                       \
        qb##t##h0 = *(const short8*)(&Kh[1][brow * LD + g * 8]);               \
        qb##t##h1 = *(const short8*)(&Kh[1][brow * LD + 32 + g * 8]);          \
        qb##t##l0 = *(const short8*)(&Kl[1][brow * LD + g * 8]);               \
        qb##t##l1 = *(const short8*)(&Kl[1][brow * LD + 32 + g * 8]);          \
    }
    QFRAG(0) QFRAG(1) QFRAG(2) QFRAG(3)
#undef QFRAG
    __syncthreads();   // buf1 free for t=0's stage-write only after all hoists

    f32x4 acc0 = {0.f,0.f,0.f,0.f}, acc1 = {0.f,0.f,0.f,0.f};
    f32x4 acc2 = {0.f,0.f,0.f,0.f}, acc3 = {0.f,0.f,0.f,0.f};
    float ssq0 = 0.f, ssq1 = 0.f, ssq2 = 0.f, ssq3 = 0.f;

    int cur = 0;
    for (int k0 = 0; k0 < Sdim; k0 += BK, cur ^= 1) {
        const bool hasn = (k0 + BK) < Sdim;
        const int  k0n  = k0 + BK;

        // ---- issue next-tile K/V loads early (named regs, no arrays) ----
        float4 kp0, kp1, kp2, kp3, vp0, vp1, vp2, vp3;
        if (hasn) {
            const float* KpN = Kp + (size_t)k0n * Ddim;
            const float* VpN = Vp + (size_t)k0n * Ddim;
            kp0 = *(const float4*)(KpN + (size_t)(r0     ) * Ddim + c4 * 4);
            kp1 = *(const float4*)(KpN + (size_t)(r0 + 16) * Ddim + c4 * 4);
            kp2 = *(const float4*)(KpN + (size_t)(r0 + 32) * Ddim + c4 * 4);
            kp3 = *(const float4*)(KpN + (size_t)(r0 + 48) * Ddim + c4 * 4);
            vp0 = *(const float4*)(VpN + (size_t)(r0     ) * Ddim + c4 * 4);
            vp1 = *(const float4*)(VpN + (size_t)(r0 + 16) * Ddim + c4 * 4);
            vp2 = *(const float4*)(VpN + (size_t)(r0 + 32) * Ddim + c4 * 4);
            vp3 = *(const float4*)(VpN + (size_t)(r0 + 48) * Ddim + c4 * 4);
        }
        // ---- issue current-tile mask loads early ----
        const int kcol = k0 + 16 * w + 4 * g;
        const int4 mm0 = *(const int4*)(Mp + (size_t)(q0      + l15) * Sdim + kcol);
        const int4 mm1 = *(const int4*)(Mp + (size_t)(q0 + 16 + l15) * Sdim + kcol);
        const int4 mm2 = *(const int4*)(Mp + (size_t)(q0 + 32 + l15) * Sdim + kcol);
        const int4 mm3 = *(const int4*)(Mp + (size_t)(q0 + 48 + l15) * Sdim + kcol);

        // ---- QK^T swapped: A = K rows (wave's 16 keys), B = hoisted Q ----
        // C layout: col=q_local=l15, row=key_local=4g+reg
        const unsigned short* KhC = Kh[cur];
        const unsigned short* KlC = Kl[cur];
        const int arow = 16 * w + l15;
        short8 aKh0 = *(const short8*)(&KhC[arow * LD + g * 8]);
        short8 aKh1 = *(const short8*)(&KhC[arow * LD + 32 + g * 8]);
        short8 aKl0 = *(const short8*)(&KlC[arow * LD + g * 8]);
        short8 aKl1 = *(const short8*)(&KlC[arow * LD + 32 + g * 8]);

#define QKT_TILE(t, sacc)                                                      \
        f32x4 sacc = {0.f, 0.f, 0.f, 0.f};                                     \
        {                                                                      \
            MFMA(sacc, aKh0, qb##t##h0); MFMA(sacc, aKh1, qb##t##h1);          \
            MFMA(sacc, aKh0, qb##t##l0); MFMA(sacc, aKh1, qb##t##l1);          \
            MFMA(sacc, aKl0, qb##t##h0); MFMA(sacc, aKl1, qb##t##h1);          \
        }
        QKT_TILE(0, s0) QKT_TILE(1, s1) QKT_TILE(2, s2) QKT_TILE(3, s3)
#undef QKT_TILE

        // ---- mask + eps, ssq accumulate (fp32), park P (prefetched mask) ----
#define PARK(t, sacc, ssq)                                                     \
        {                                                                      \
            float x0 = mm##t.x ? sacc.x + 1e-5f : 0.f;                         \
            float x1 = mm##t.y ? sacc.y + 1e-5f : 0.f;                         \
            float x2 = mm##t.z ? sacc.z + 1e-5f : 0.f;                         \
            float x3 = mm##t.w ? sacc.w + 1e-5f : 0.f;                         \
            ssq += x0 * x0 + x1 * x1 + x2 * x2 + x3 * x3;                      \
            int po = (16 * (t) + l15) * LD + 16 * w + 4 * g;                   \
            *(uint2*)(&Ph[po]) = make_uint2(bf_hi(x0) | (bf_hi(x1) << 16),     \
                                            bf_hi(x2) | (bf_hi(x3) << 16));   \
        }
        PARK(0, s0, ssq0) PARK(1, s1, ssq1) PARK(2, s2, ssq2) PARK(3, s3, ssq3)
#undef PARK

        // ---- write prefetched K/V into the idle buffer (no reader until bar) ----
        if (hasn) {
            unsigned short* KhN = Kh[cur ^ 1];
            unsigned short* KlN = Kl[cur ^ 1];
            unsigned short* VhN = Vh[cur ^ 1];
            KSTAGE_W(KhN, KlN, r0,      kp0);
            KSTAGE_W(KhN, KlN, r0 + 16, kp1);
            KSTAGE_W(KhN, KlN, r0 + 32, kp2);
            KSTAGE_W(KhN, KlN, r0 + 48, kp3);
            VSTAGE_W(VhN, r0,      vp0);
            VSTAGE_W(VhN, r0 + 16, vp1);
            VSTAGE_W(VhN, r0 + 32, vp2);
            VSTAGE_W(VhN, r0 + 48, vp3);
        }
        __syncthreads();   // barrier 1: Ph + next buffers ready

        // ---- PV: A = P rows (wave's 16 q), B = V^T (swizzled blocks) ----
        const unsigned short* VhC = Vh[cur];
        const int prow = 16 * w + l15;
        short8 aPh0 = *(const short8*)(&Ph[prow * LD + g * 8]);
        short8 aPh1 = *(const short8*)(&Ph[prow * LD + 32 + g * 8]);

#define PV_TILE(t, acc)                                                        \
        {                                                                      \
            const int drow = 16 * (t) + l15;                                   \
            const int sw = drow >> 3;                                          \
            short8 vb0 = *(const short8*)(&VhC[drow * LD + (((0 + g) ^ sw) << 3)]); \
            short8 vb1 = *(const short8*)(&VhC[drow * LD + (((4 + g) ^ sw) << 3)]); \
            MFMA(acc, aPh0, vb0); MFMA(acc, aPh1, vb1);                        \
        }
        PV_TILE(0, acc0) PV_TILE(1, acc1) PV_TILE(2, acc2) PV_TILE(3, acc3)
#undef PV_TILE
        __syncthreads();   // barrier 2: done reading Ph/buf[cur] before next writes
    }

    // ---- ssq: reduce over key-groups in-wave, then across waves via LDS ----
    ssq0 += __shfl_xor(ssq0, 16, 64); ssq0 += __shfl_xor(ssq0, 32, 64);
    ssq1 += __shfl_xor(ssq1, 16, 64); ssq1 += __shfl_xor(ssq1, 32, 64);
    ssq2 += __shfl_xor(ssq2, 16, 64); ssq2 += __shfl_xor(ssq2, 32, 64);
    ssq3 += __shfl_xor(ssq3, 16, 64); ssq3 += __shfl_xor(ssq3, 32, 64);
    if (lane < 16) {
        ssq_tab[w][l15]      = ssq0;
        ssq_tab[w][16 + l15] = ssq1;
        ssq_tab[w][32 + l15] = ssq2;
        ssq_tab[w][48 + l15] = ssq3;
    }
    __syncthreads();

    // ---- scale rows by 1/max(||s||,1e-12) and store ----
#define OUTR(reg, comp)                                                        \
    {                                                                          \
        const int q = 16 * w + 4 * g + (reg);                                  \
        float sum = ssq_tab[0][q] + ssq_tab[1][q] + ssq_tab[2][q] + ssq_tab[3][q]; \
        float rn = 1.0f / fmaxf(sqrtf(sum), 1e-12f);                           \
        float* orow = Op + (size_t)(q0 + q) * Ddim + l15;                      \
        orow[0]  = acc0.comp * rn;                                             \
        orow[16] = acc1.comp * rn;                                             \
        orow[32] = acc2.comp * rn;                                             \
        orow[48] = acc3.comp * rn;                                             \
    }
    OUTR(0, x) OUTR(1, y) OUTR(2, z) OUTR(3, w)
#undef OUTR
}

extern "C" void kernel_launch(void* const* d_in, const int* in_sizes, int n_in,
                              void* d_out, int out_size, void* d_ws, size_t ws_size,
                              hipStream_t stream) {
    const float* Q = (const float*)d_in[0];
    const float* K = (const float*)d_in[1];
    const float* V = (const float*)d_in[2];
    const int*   M = (const int*)d_in[3];
    float*       O = (float*)d_out;

    const int BH = in_sizes[0] / (Sdim * Ddim);  // B*H = 32
    dim3 grid(Sdim / BQ, BH);
    lka_mfma<<<grid, dim3(256), 0, stream>>>(Q, K, V, M, O);
}

// Round 15
// 254.148 us; speedup vs baseline: 2.0001x; 1.0564x over previous
//
#include <hip/hip_runtime.h>
#include <hip/hip_bf16.h>

// LinearKernelAttention: out = normalize_row(mask0(QK^T + 1e-5)) @ V
// R13 result: async-stage split = neutral (195us) -> VMEM latency not on
// critical path. VALU (41%, mostly manual bf16-conversion bit-ops) is the
// top pipe and sits serially between MFMA phases.
// R14: (1) manual bf_hi -> __float2bfloat16 casts (RNE-identical; compiler
// emits v_cvt_pk_bf16_f32: ~1 instr/2 values vs ~10); (2) drop Kl: K is
// single-bf16, QK^T 24->16 MFMA, Kl staging deleted (error adds ~15% in
// quadrature to existing P/V-bf16 error; absmax predicted <= 0.0625).
// Ql parks in Vh[1] during the prologue (Kl buffer gone). LDS 47KB.
// R15: resubmitted unchanged (R14 bench lost to GPU acquisition timeout).
//
// Shapes: B=2, H=16, S=2048, D=64, fp32 in/out, mask int32 [B,1,S,S].

constexpr int Sdim = 2048;
constexpr int Ddim = 64;
constexpr int BQ = 64;
constexpr int BK = 64;
constexpr int LD = 72;   // bf16 elems/row: 144B rows -> 16B-aligned, bank-balanced

typedef __attribute__((ext_vector_type(8))) short short8;
typedef __attribute__((ext_vector_type(4))) float f32x4;

#define MFMA(acc, a, b) (acc) = __builtin_amdgcn_mfma_f32_16x16x32_bf16((a), (b), (acc), 0, 0, 0)

__device__ __forceinline__ unsigned f2bfu(float x) {   // RNE via HW cvt
    union { __hip_bfloat16 b; unsigned short u; } c;
    c.b = __float2bfloat16(x);
    return (unsigned)c.u;
}
__device__ __forceinline__ float bfu2f(unsigned u) {
    union { unsigned short u; __hip_bfloat16 b; } c;
    c.u = (unsigned short)u;
    return __bfloat162float(c.b);
}

__global__ __launch_bounds__(256, 2) void lka_mfma(
    const float* __restrict__ Q, const float* __restrict__ K,
    const float* __restrict__ V, const int* __restrict__ M,
    float* __restrict__ O)
{
    __shared__ unsigned short Kh[2][BK * LD];
    __shared__ unsigned short Vh[2][Ddim * LD];  // transposed [d][key], key-blocks swizzled by d>>3
    __shared__ unsigned short Ph[BQ * LD];
    __shared__ float ssq_tab[4][BQ];

    const int tid  = threadIdx.x;
    const int w    = tid >> 6;        // wave 0..3
    const int lane = tid & 63;
    const int l15  = lane & 15;
    const int g    = lane >> 4;       // 0..3
    const int r0   = tid >> 4;        // staging row base 0..15
    const int c4   = tid & 15;        // staging col group
    const int bh   = blockIdx.y;
    const int b    = bh >> 4;         // H = 16
    const int q0   = blockIdx.x * BQ;

    const float* Qp = Q + (size_t)bh * Sdim * Ddim;
    const float* Kp = K + (size_t)bh * Sdim * Ddim;
    const float* Vp = V + (size_t)bh * Sdim * Ddim;
    const int*   Mp = M + (size_t)b * Sdim * Sdim;
    float*       Op = O + (size_t)bh * Sdim * Ddim;

    // single-bf16 row-major write of one float4 (K-style)
#define KSTAGE_W(dstH, row, vreg)                                              \
    *(uint2*)(&dstH[(row) * LD + c4 * 4]) = make_uint2(                        \
        f2bfu(vreg.x) | (f2bfu(vreg.y) << 16),                                 \
        f2bfu(vreg.z) | (f2bfu(vreg.w) << 16));

    // transposed+swizzled single-bf16 write of one float4 (V-style)
#define VSTAGE_W(dstV, row, vreg)                                              \
    {                                                                          \
        int kb = (row) >> 3, ko = (row) & 7;                                   \
        { int d = c4 * 4 + 0; dstV[d * LD + (((kb ^ (d >> 3)) << 3) | ko)] = (unsigned short)f2bfu(vreg.x); } \
        { int d = c4 * 4 + 1; dstV[d * LD + (((kb ^ (d >> 3)) << 3) | ko)] = (unsigned short)f2bfu(vreg.y); } \
        { int d = c4 * 4 + 2; dstV[d * LD + (((kb ^ (d >> 3)) << 3) | ko)] = (unsigned short)f2bfu(vreg.z); } \
        { int d = c4 * 4 + 3; dstV[d * LD + (((kb ^ (d >> 3)) << 3) | ko)] = (unsigned short)f2bfu(vreg.w); } \
    }

    // ---- prologue: Q hi -> Kh[1], Q lo -> Vh[1]; K/V tile0 -> buf0 ----
#pragma unroll
    for (int it = 0; it < 4; ++it) {
        const int row = r0 + 16 * it;
        float4 qv = *(const float4*)(Qp + (size_t)(q0 + row) * Ddim + c4 * 4);
        {
            unsigned h0 = f2bfu(qv.x), h1 = f2bfu(qv.y), h2 = f2bfu(qv.z), h3 = f2bfu(qv.w);
            *(uint2*)(&Kh[1][row * LD + c4 * 4]) = make_uint2(h0 | (h1 << 16), h2 | (h3 << 16));
            *(uint2*)(&Vh[1][row * LD + c4 * 4]) = make_uint2(
                f2bfu(qv.x - bfu2f(h0)) | (f2bfu(qv.y - bfu2f(h1)) << 16),
                f2bfu(qv.z - bfu2f(h2)) | (f2bfu(qv.w - bfu2f(h3)) << 16));
        }
        float4 kv = *(const float4*)(Kp + (size_t)row * Ddim + c4 * 4);
        KSTAGE_W(Kh[0], row, kv);
        float4 vv = *(const float4*)(Vp + (size_t)row * Ddim + c4 * 4);
        VSTAGE_W(Vh[0], row, vv);
    }
    __syncthreads();

    // ---- hoist Q fragments to registers (hi from Kh[1], lo from Vh[1]) ----
#define QFRAG(t)                                                               \
    short8 qb##t##h0, qb##t##h1, qb##t##l0, qb##t##l1;                         \
    {                                                                          \
        const int brow = 16 * (t) + l15;                                       \
        qb##t##h0 = *(const short8*)(&Kh[1][brow * LD + g * 8]);               \
        qb##t##h1 = *(const short8*)(&Kh[1][brow * LD + 32 + g * 8]);          \
        qb##t##l0 = *(const short8*)(&Vh[1][brow * LD + g * 8]);               \
        qb##t##l1 = *(const short8*)(&Vh[1][brow * LD + 32 + g * 8]);          \
    }
    QFRAG(0) QFRAG(1) QFRAG(2) QFRAG(3)
#undef QFRAG
    __syncthreads();   // buf1 free for tile-1 stage-writes only after all hoists

    f32x4 acc0 = {0.f,0.f,0.f,0.f}, acc1 = {0.f,0.f,0.f,0.f};
    f32x4 acc2 = {0.f,0.f,0.f,0.f}, acc3 = {0.f,0.f,0.f,0.f};
    float ssq0 = 0.f, ssq1 = 0.f, ssq2 = 0.f, ssq3 = 0.f;

    int cur = 0;
    for (int k0 = 0; k0 < Sdim; k0 += BK, cur ^= 1) {
        const bool hasn = (k0 + BK) < Sdim;
        const int  k0n  = k0 + BK;

        // ---- issue next-tile K/V loads early (named regs) ----
        float4 kp0, kp1, kp2, kp3, vp0, vp1, vp2, vp3;
        if (hasn) {
            const float* KpN = Kp + (size_t)k0n * Ddim;
            const float* VpN = Vp + (size_t)k0n * Ddim;
            kp0 = *(const float4*)(KpN + (size_t)(r0     ) * Ddim + c4 * 4);
            kp1 = *(const float4*)(KpN + (size_t)(r0 + 16) * Ddim + c4 * 4);
            kp2 = *(const float4*)(KpN + (size_t)(r0 + 32) * Ddim + c4 * 4);
            kp3 = *(const float4*)(KpN + (size_t)(r0 + 48) * Ddim + c4 * 4);
            vp0 = *(const float4*)(VpN + (size_t)(r0     ) * Ddim + c4 * 4);
            vp1 = *(const float4*)(VpN + (size_t)(r0 + 16) * Ddim + c4 * 4);
            vp2 = *(const float4*)(VpN + (size_t)(r0 + 32) * Ddim + c4 * 4);
            vp3 = *(const float4*)(VpN + (size_t)(r0 + 48) * Ddim + c4 * 4);
        }
        // ---- issue current-tile mask loads early ----
        const int kcol = k0 + 16 * w + 4 * g;
        const int4 mm0 = *(const int4*)(Mp + (size_t)(q0      + l15) * Sdim + kcol);
        const int4 mm1 = *(const int4*)(Mp + (size_t)(q0 + 16 + l15) * Sdim + kcol);
        const int4 mm2 = *(const int4*)(Mp + (size_t)(q0 + 32 + l15) * Sdim + kcol);
        const int4 mm3 = *(const int4*)(Mp + (size_t)(q0 + 48 + l15) * Sdim + kcol);

        // ---- QK^T swapped: A = K rows (single bf16), B = hoisted Q hi+lo ----
        // C layout: col=q_local=l15, row=key_local=4g+reg
        const unsigned short* KhC = Kh[cur];
        const int arow = 16 * w + l15;
        short8 aKh0 = *(const short8*)(&KhC[arow * LD + g * 8]);
        short8 aKh1 = *(const short8*)(&KhC[arow * LD + 32 + g * 8]);

#define QKT_TILE(t, sacc)                                                      \
        f32x4 sacc = {0.f, 0.f, 0.f, 0.f};                                     \
        {                                                                      \
            MFMA(sacc, aKh0, qb##t##h0); MFMA(sacc, aKh1, qb##t##h1);          \
            MFMA(sacc, aKh0, qb##t##l0); MFMA(sacc, aKh1, qb##t##l1);          \
        }
        QKT_TILE(0, s0) QKT_TILE(1, s1) QKT_TILE(2, s2) QKT_TILE(3, s3)
#undef QKT_TILE

        // ---- mask + eps, ssq accumulate (fp32), park P (cvt_pk path) ----
#define PARK(t, sacc, ssq)                                                     \
        {                                                                      \
            float x0 = mm##t.x ? sacc.x + 1e-5f : 0.f;                         \
            float x1 = mm##t.y ? sacc.y + 1e-5f : 0.f;                         \
            float x2 = mm##t.z ? sacc.z + 1e-5f : 0.f;                         \
            float x3 = mm##t.w ? sacc.w + 1e-5f : 0.f;                         \
            ssq += x0 * x0 + x1 * x1 + x2 * x2 + x3 * x3;                      \
            int po = (16 * (t) + l15) * LD + 16 * w + 4 * g;                   \
            *(uint2*)(&Ph[po]) = make_uint2(f2bfu(x0) | (f2bfu(x1) << 16),     \
                                            f2bfu(x2) | (f2bfu(x3) << 16));   \
        }
        PARK(0, s0, ssq0) PARK(1, s1, ssq1) PARK(2, s2, ssq2) PARK(3, s3, ssq3)
#undef PARK

        // ---- write prefetched K/V into the idle buffer ----
        if (hasn) {
            unsigned short* KhN = Kh[cur ^ 1];
            unsigned short* VhN = Vh[cur ^ 1];
            KSTAGE_W(KhN, r0,      kp0);
            KSTAGE_W(KhN, r0 + 16, kp1);
            KSTAGE_W(KhN, r0 + 32, kp2);
            KSTAGE_W(KhN, r0 + 48, kp3);
            VSTAGE_W(VhN, r0,      vp0);
            VSTAGE_W(VhN, r0 + 16, vp1);
            VSTAGE_W(VhN, r0 + 32, vp2);
            VSTAGE_W(VhN, r0 + 48, vp3);
        }
        __syncthreads();   // barrier 1: Ph + next buffers ready

        // ---- PV: A = P rows (wave's 16 q), B = V^T (swizzled blocks) ----
        const unsigned short* VhC = Vh[cur];
        const int prow = 16 * w + l15;
        short8 aPh0 = *(const short8*)(&Ph[prow * LD + g * 8]);
        short8 aPh1 = *(const short8*)(&Ph[prow * LD + 32 + g * 8]);

#define PV_TILE(t, acc)                                                        \
        {                                                                      \
            const int drow = 16 * (t) + l15;                                   \
            const int sw = drow >> 3;                                          \
            short8 vb0 = *(const short8*)(&VhC[drow * LD + (((0 + g) ^ sw) << 3)]); \
            short8 vb1 = *(const short8*)(&VhC[drow * LD + (((4 + g) ^ sw) << 3)]); \
            MFMA(acc, aPh0, vb0); MFMA(acc, aPh1, vb1);                        \
        }
        PV_TILE(0, acc0) PV_TILE(1, acc1) PV_TILE(2, acc2) PV_TILE(3, acc3)
#undef PV_TILE
        __syncthreads();   // barrier 2: done reading Ph/buf[cur] before next writes
    }

    // ---- ssq: reduce over key-groups in-wave, then across waves via LDS ----
    ssq0 += __shfl_xor(ssq0, 16, 64); ssq0 += __shfl_xor(ssq0, 32, 64);
    ssq1 += __shfl_xor(ssq1, 16, 64); ssq1 += __shfl_xor(ssq1, 32, 64);
    ssq2 += __shfl_xor(ssq2, 16, 64); ssq2 += __shfl_xor(ssq2, 32, 64);
    ssq3 += __shfl_xor(ssq3, 16, 64); ssq3 += __shfl_xor(ssq3, 32, 64);
    if (lane < 16) {
        ssq_tab[w][l15]      = ssq0;
        ssq_tab[w][16 + l15] = ssq1;
        ssq_tab[w][32 + l15] = ssq2;
        ssq_tab[w][48 + l15] = ssq3;
    }
    __syncthreads();

    // ---- scale rows by 1/max(||s||,1e-12) and store ----
#define OUTR(reg, comp)                                                        \
    {                                                                          \
        const int q = 16 * w + 4 * g + (reg);                                  \
        float sum = ssq_tab[0][q] + ssq_tab[1][q] + ssq_tab[2][q] + ssq_tab[3][q]; \
        float rn = 1.0f / fmaxf(sqrtf(sum), 1e-12f);                           \
        float* orow = Op + (size_t)(q0 + q) * Ddim + l15;                      \
        orow[0]  = acc0.comp * rn;                                             \
        orow[16] = acc1.comp * rn;                                             \
        orow[32] = acc2.comp * rn;                                             \
        orow[48] = acc3.comp * rn;                                             \
    }
    OUTR(0, x) OUTR(1, y) OUTR(2, z) OUTR(3, w)
#undef OUTR
}

extern "C" void kernel_launch(void* const* d_in, const int* in_sizes, int n_in,
                              void* d_out, int out_size, void* d_ws, size_t ws_size,
                              hipStream_t stream) {
    const float* Q = (const float*)d_in[0];
    const float* K = (const float*)d_in[1];
    const float* V = (const float*)d_in[2];
    const int*   M = (const int*)d_in[3];
    float*       O = (float*)d_out;

    const int BH = in_sizes[0] / (Sdim * Ddim);  // B*H = 32
    dim3 grid(Sdim / BQ, BH);
    lka_mfma<<<grid, dim3(256), 0, stream>>>(Q, K, V, M, O);
}